// Round 11
// baseline (192.291 us; speedup 1.0000x reference)
//
#include <hip/hip_runtime.h>
#include <math.h>

#define NPTS 262144
#define BATCH 32
#define BPB 16
#define NBLK (BATCH * BPB)   // 512 blocks x 256t: fastest measured main config
#define ITERS 16             // compile-time -> full unroll + reg double-buffer
#define NREP 8               // replicas for global accumulators

// ws layout (bytes), ALL zero-init by one memset:
//   0    : float gsum[NREP][11]   (S[5], T[5], lse)
//   352  : uint  gcnt[NREP][5]    (bincount)
//   512  : float bsum[32][8]      (gtz[4], prz[4])
//   1536 : uint  bcnt[32][8]      (gtc[4], prc[4])
//   2560 : uint  bmx [32][4]      (mapf(mx):  2x,2y,3x,3y)   max, 0-init ok
//   3072 : uint  bmn [32][4]      (mapf(-mn): 2x,2y,3x,3y)   max, 0-init ok
//   3584 : end
// min is tracked as max of mapf(-x): block mins are always <= 0 (mask-zeros
// included), so mapped values are >= 0x80000000 > 0 => zero-init is identity.

__device__ __forceinline__ float wred_sum(float v) {
#pragma unroll
    for (int o = 32; o; o >>= 1) v += __shfl_down(v, o);
    return v;
}
__device__ __forceinline__ unsigned wred_usum(unsigned v) {
#pragma unroll
    for (int o = 32; o; o >>= 1) v += __shfl_down(v, o);
    return v;
}

// order-preserving float->uint map (monotonic)
__device__ __forceinline__ unsigned mapf(float f) {
    unsigned u = __float_as_uint(f);
    return (u & 0x80000000u) ? ~u : (u | 0x80000000u);
}
__device__ __forceinline__ float unmapf(unsigned m) {
    return (m & 0x80000000u) ? __uint_as_float(m ^ 0x80000000u)
                             : __uint_as_float(~m);
}

struct Grp {
    float4 L0, L1, L2, L3, L4;
    int4   lab;
    float4 p0, p1, p2;
};

__device__ __forceinline__ Grp ldgrp(const float* __restrict__ obase,
                                     const int* __restrict__ lbase,
                                     const float* __restrict__ pbase, int n) {
    Grp g;
    g.L0 = *(const float4*)(obase + (size_t)0 * NPTS + n);
    g.L1 = *(const float4*)(obase + (size_t)1 * NPTS + n);
    g.L2 = *(const float4*)(obase + (size_t)2 * NPTS + n);
    g.L3 = *(const float4*)(obase + (size_t)3 * NPTS + n);
    g.L4 = *(const float4*)(obase + (size_t)4 * NPTS + n);
    g.lab = *(const int4*)(lbase + n);
    const float4* pp = (const float4*)(pbase + (size_t)n * 3);
    g.p0 = pp[0]; g.p1 = pp[1]; g.p2 = pp[2];
    return g;
}

struct Acc {
    float S[5], T[5], lse;
    float gtz[4], prz[4];
    float mn2x, mx2x, mn2y, mx2y, mn3x, mx3x, mn3y, mx3y;
    unsigned bc[5], prc[4];
};

__device__ __forceinline__ void process(const Grp& g, Acc& a) {
    const float xs[4] = {g.p0.x, g.p0.w, g.p1.z, g.p2.y};
    const float ys[4] = {g.p0.y, g.p1.x, g.p1.w, g.p2.z};
    const float zs[4] = {g.p0.z, g.p1.y, g.p2.x, g.p2.w};
    const int   lb[4] = {g.lab.x, g.lab.y, g.lab.z, g.lab.w};
#pragma unroll
    for (int j = 0; j < 4; ++j) {
        float v[5];
        v[0] = ((const float*)&g.L0)[j];
        v[1] = ((const float*)&g.L1)[j];
        v[2] = ((const float*)&g.L2)[j];
        v[3] = ((const float*)&g.L3)[j];
        v[4] = ((const float*)&g.L4)[j];
        // first-max argmax (JAX tie-break semantics)
        float best = v[0]; int pred = 0;
#pragma unroll
        for (int c = 1; c < 5; ++c)
            if (v[c] > best) { best = v[c]; pred = c; }
        float e = 0.f;
#pragma unroll
        for (int c = 0; c < 5; ++c) e += __expf(v[c] - best);
        const float lse = best + __logf(e);
        a.lse += lse;
        const int y = lb[j];
#pragma unroll
        for (int c = 0; c < 5; ++c) {
            a.S[c] += v[c];
            const bool is = (y == c);
            a.T[c] += is ? (lse - v[c]) : 0.f;
            a.bc[c] += is ? 1u : 0u;
        }
        const float z = zs[j];
#pragma unroll
        for (int k = 0; k < 4; ++k) {
            const bool gy = (y == k + 1), py = (pred == k + 1);
            a.gtz[k] += gy ? z : 0.f;
            a.prz[k] += py ? z : 0.f;
            a.prc[k] += py ? 1u : 0u;
        }
        const float x = xs[j], yv = ys[j];
        // reference: mp = points*mask -> zeros included in min/max
        const float a2x = (pred == 2) ? x : 0.f;
        const float a2y = (pred == 2) ? yv : 0.f;
        const float a3x = (pred == 3) ? x : 0.f;
        const float a3y = (pred == 3) ? yv : 0.f;
        a.mn2x = fminf(a.mn2x, a2x); a.mx2x = fmaxf(a.mx2x, a2x);
        a.mn2y = fminf(a.mn2y, a2y); a.mx2y = fmaxf(a.mx2y, a2y);
        a.mn3x = fminf(a.mn3x, a3x); a.mx3x = fmaxf(a.mx3x, a3x);
        a.mn3y = fminf(a.mn3y, a3y); a.mx3y = fmaxf(a.mx3y, a3y);
    }
}

__global__ __launch_bounds__(256) void bsl_main(
    const float* __restrict__ outputs, const int* __restrict__ labels,
    const float* __restrict__ points,
    float* gsum, unsigned* gcnt, float* bsum, unsigned* bcnt,
    unsigned* bmn, unsigned* bmx)
{
    const int blk = blockIdx.x;
    const int b = blk / BPB;
    const int seg = blk % BPB;
    const int tid = threadIdx.x;
    const int base_n = seg * (ITERS * 1024) + tid * 4;

    Acc a;
#pragma unroll
    for (int c = 0; c < 5; ++c) { a.S[c] = 0.f; a.T[c] = 0.f; a.bc[c] = 0u; }
    a.lse = 0.f;
#pragma unroll
    for (int k = 0; k < 4; ++k) { a.gtz[k] = 0.f; a.prz[k] = 0.f; a.prc[k] = 0u; }
    const float INF = __int_as_float(0x7f800000);
    a.mn2x = INF; a.mx2x = -INF; a.mn2y = INF; a.mx2y = -INF;
    a.mn3x = INF; a.mx3x = -INF; a.mn3y = INF; a.mx3y = -INF;

    const float* obase = outputs + (size_t)b * 5 * NPTS;
    const int*   lbase = labels + (size_t)b * NPTS;
    const float* pbase = points + (size_t)b * NPTS * 3;

    // register double-buffer: one 9-load group always in flight under compute
    Grp gA = ldgrp(obase, lbase, pbase, base_n);
    Grp gB = ldgrp(obase, lbase, pbase, base_n + 1024);
#pragma unroll
    for (int it = 0; it < ITERS; it += 2) {
        process(gA, a);
        if (it + 2 < ITERS) gA = ldgrp(obase, lbase, pbase, base_n + (it + 2) * 1024);
        process(gB, a);
        if (it + 3 < ITERS) gB = ldgrp(obase, lbase, pbase, base_n + (it + 3) * 1024);
    }

    float fv[27] = {a.S[0], a.S[1], a.S[2], a.S[3], a.S[4],
                    a.T[0], a.T[1], a.T[2], a.T[3], a.T[4],
                    a.lse,
                    a.gtz[0], a.gtz[1], a.gtz[2], a.gtz[3],
                    a.prz[0], a.prz[1], a.prz[2], a.prz[3],
                    a.mn2x, a.mx2x, a.mn2y, a.mx2y, a.mn3x, a.mx3x, a.mn3y, a.mx3y};
    unsigned iv[9] = {a.bc[0], a.bc[1], a.bc[2], a.bc[3], a.bc[4],
                      a.prc[0], a.prc[1], a.prc[2], a.prc[3]};

    __shared__ float sf[4][27];
    __shared__ unsigned si[4][9];
    const int wid = tid >> 6, lane = tid & 63;
#pragma unroll
    for (int vdx = 0; vdx < 27; ++vdx) {
        float r;
        if (vdx < 19) r = wred_sum(fv[vdx]);
        else if (((vdx - 19) & 1) == 0) {
#pragma unroll
            for (int o = 32; o; o >>= 1) fv[vdx] = fminf(fv[vdx], __shfl_down(fv[vdx], o));
            r = fv[vdx];
        } else {
#pragma unroll
            for (int o = 32; o; o >>= 1) fv[vdx] = fmaxf(fv[vdx], __shfl_down(fv[vdx], o));
            r = fv[vdx];
        }
        if (lane == 0) sf[wid][vdx] = r;
    }
#pragma unroll
    for (int vdx = 0; vdx < 9; ++vdx) {
        unsigned r = wred_usum(iv[vdx]);
        if (lane == 0) si[wid][vdx] = r;
    }
    __syncthreads();

    // cross-wave combine + ONE relaxed atomic per value (no cache maintenance)
    const int rep = blk & (NREP - 1);
    if (tid < 27) {
        float r = sf[0][tid];
        if (tid < 19) {
            r += sf[1][tid] + sf[2][tid] + sf[3][tid];
        } else if (((tid - 19) & 1) == 0) {
            r = fminf(fminf(r, sf[1][tid]), fminf(sf[2][tid], sf[3][tid]));
        } else {
            r = fmaxf(fmaxf(r, sf[1][tid]), fmaxf(sf[2][tid], sf[3][tid]));
        }
        if (tid < 11) {
            atomicAdd(&gsum[rep * 11 + tid], r);
        } else if (tid < 19) {
            atomicAdd(&bsum[b * 8 + (tid - 11)], r);
        } else {
            const int g = tid - 19;            // 0..7: (mn,mx)x{2x,2y,3x,3y}
            if ((g & 1) == 0) atomicMax(&bmn[b * 4 + (g >> 1)], mapf(-r)); // min
            else              atomicMax(&bmx[b * 4 + (g >> 1)], mapf(r));  // max
        }
    } else if (tid >= 32 && tid < 41) {
        const int v = tid - 32;
        const unsigned r = si[0][v] + si[1][v] + si[2][v] + si[3][v];
        if (v < 5) {
            atomicAdd(&gcnt[rep * 5 + v], r);
            if (v >= 1) atomicAdd(&bcnt[b * 8 + (v - 1)], r);  // gtc = label cnt 1..4
        } else {
            atomicAdd(&bcnt[b * 8 + 4 + (v - 5)], r);          // prc
        }
    }
}

// Tiny finalize: 1 block x 64 threads, reads 3.5 KB.
__global__ __launch_bounds__(64) void bsl_final(
    const float* __restrict__ gsum, const unsigned* __restrict__ gcnt,
    const float* __restrict__ bsum, const unsigned* __restrict__ bcnt,
    const unsigned* __restrict__ bmn, const unsigned* __restrict__ bmx,
    float* __restrict__ out)
{
    const int lane = threadIdx.x;
    __shared__ float smg[16];   // 0..10 S/T/lse, 11..15 dist

    if (lane < 16) {
        float s = 0.f;
        if (lane < 11) {
#pragma unroll
            for (int r = 0; r < NREP; ++r) s += gsum[r * 11 + lane];
        } else {
            unsigned u = 0;
#pragma unroll
            for (int r = 0; r < NREP; ++r) u += gcnt[r * 5 + (lane - 11)];
            s = (float)u;   // exact: <= 2^23
        }
        smg[lane] = s;
    }

    const float BASE_W[5] = {0.8f, 2.0f, 1.5f, 1.5f, 3.5f};
    const int pc[12]  = {1, 1, 1, 2, 2, 2, 3, 3, 3, 4, 4, 4};
    const int prf[12] = {2, 3, 4, 1, 3, 4, 1, 2, 4, 1, 2, 3};
    const float ps[12] = {-1.f, -1.f, -1.f, 1.f, -1.f, -1.f, 1.f, 1.f, -1.f, 1.f, 1.f, 1.f};

    // lane b (< BATCH) computes batch b's clipped weights; others contribute 0
    float w[5] = {0, 0, 0, 0, 0};
    if (lane < BATCH) {
        for (int c = 0; c < 5; ++c) w[c] = BASE_W[c];
        float gtm[4], prm[4];
        bool gv[4], pv[4];
#pragma unroll
        for (int k = 0; k < 4; ++k) {
            const unsigned c1 = bcnt[lane * 8 + k];
            gv[k] = (c1 > 0u);
            gtm[k] = bsum[lane * 8 + k] / fmaxf((float)c1, 1.f);
            const unsigned c2 = bcnt[lane * 8 + 4 + k];
            pv[k] = (c2 > 0u);
            prm[k] = bsum[lane * 8 + 4 + k] / fmaxf((float)c2, 1.f);
        }
#pragma unroll
        for (int p = 0; p < 12; ++p) {
            const int cid = pc[p], ref = prf[p];
            float add = 0.f;
            if (pv[cid - 1] && gv[ref - 1]) {
                const float diff = ps[p] * (prm[cid - 1] - gtm[ref - 1]);
                add = 50.f / (1.f + expf(10.f * diff));  // ALPHA*sigmoid(-10*diff)
            }
            w[cid] += add;
            w[ref] += 0.3f * add;
        }
        // mins stored as mapf(-mn) under atomicMax -> mn = -unmapf(stored)
        const float mn2x = -unmapf(bmn[lane * 4 + 0]), mx2x = unmapf(bmx[lane * 4 + 0]);
        const float mn2y = -unmapf(bmn[lane * 4 + 1]), mx2y = unmapf(bmx[lane * 4 + 1]);
        const float mn3x = -unmapf(bmn[lane * 4 + 2]), mx3x = unmapf(bmx[lane * 4 + 2]);
        const float mn3y = -unmapf(bmn[lane * 4 + 3]), mx3y = unmapf(bmx[lane * 4 + 3]);
        {   // cid=2 vs rb=bounds[3]
            const float dx = mx3x - mn3x + 1e-7f, dy = mx3y - mn3y + 1e-7f;
            const float xc0 = (mn2x - mn3x) / dx, xc1 = (mx2x - mn3x) / dx;
            const float yc0 = (mn2y - mn3y) / dy, yc1 = (mx2y - mn3y) / dy;
            const float v0 = (xc0 < 0.1f || xc0 > 0.9f || yc0 < 0.1f || yc0 > 0.9f) ? 1.f : 0.f;
            const float v1 = (xc1 < 0.1f || xc1 > 0.9f || yc1 < 0.1f || yc1 > 0.9f) ? 1.f : 0.f;
            w[2] += 50.f * 0.5f * (v0 + v1);
        }
        {   // cid=3 vs rb=bounds[2]
            const float dx = mx2x - mn2x + 1e-7f, dy = mx2y - mn2y + 1e-7f;
            const float xc0 = (mn3x - mn2x) / dx, xc1 = (mx3x - mn2x) / dx;
            const float yc0 = (mn3y - mn2y) / dy, yc1 = (mx3y - mn2y) / dy;
            const float v0 = (xc0 < 0.1f || xc0 > 0.9f || yc0 < 0.1f || yc0 > 0.9f) ? 1.f : 0.f;
            const float v1 = (xc1 < 0.1f || xc1 > 0.9f || yc1 < 0.1f || yc1 > 0.9f) ? 1.f : 0.f;
            w[3] += 50.f * 0.5f * (v0 + v1);
        }
#pragma unroll
        for (int c = 0; c < 5; ++c)
            w[c] = fminf(fmaxf(w[c], 0.1f), 10.f);
    }
    float wsumc[5];
#pragma unroll
    for (int c = 0; c < 5; ++c) wsumc[c] = wred_sum(w[c]);

    __syncthreads();
    if (lane == 0) {
        float dist[5], cw[5], s = 0.f;
#pragma unroll
        for (int c = 0; c < 5; ++c) {
            dist[c] = smg[11 + c];
            cw[c] = 1.f / (sqrtf(dist[c]) + 1e-7f);
            s += cw[c];
        }
        float wf[5], wsum = 0.f, W = 0.f, nllnum = 0.f, Ssum = 0.f;
#pragma unroll
        for (int c = 0; c < 5; ++c) {
            cw[c] = cw[c] / s * 5.f;
            wf[c] = (wsumc[c] / 32.f) * cw[c];
            wsum += wf[c] * dist[c];
            W += wf[c];
            nllnum += wf[c] * smg[5 + c];
            Ssum += wf[c] * smg[c];
        }
        const float nll = nllnum / wsum;
        const float smooth = (W * smg[10] - Ssum) / wsum;
        out[0] = 0.8f * nll + 0.04f * smooth;
    }
}

extern "C" void kernel_launch(void* const* d_in, const int* in_sizes, int n_in,
                              void* d_out, int out_size, void* d_ws, size_t ws_size,
                              hipStream_t stream) {
    const float* outputs = (const float*)d_in[0];
    const int*   labels  = (const int*)d_in[1];
    const float* points  = (const float*)d_in[2];
    float* out = (float*)d_out;

    char* base = (char*)d_ws;
    float*    gsum = (float*)(base + 0);      // 8*11 f
    unsigned* gcnt = (unsigned*)(base + 352); // 8*5  u
    float*    bsum = (float*)(base + 512);    // 32*8 f
    unsigned* bcnt = (unsigned*)(base + 1536);// 32*8 u
    unsigned* bmx  = (unsigned*)(base + 2560);// 32*4 u (mapped max)
    unsigned* bmn  = (unsigned*)(base + 3072);// 32*4 u (mapped -min, max-tracked)

    hipMemsetAsync(base, 0, 3584, stream);    // single init node (0 = identity)
    bsl_main<<<NBLK, 256, 0, stream>>>(outputs, labels, points,
                                       gsum, gcnt, bsum, bcnt, bmn, bmx);
    bsl_final<<<1, 64, 0, stream>>>(gsum, gcnt, bsum, bcnt, bmn, bmx, out);
}

// Round 12
// 76.354 us; speedup vs baseline: 2.5184x; 2.5184x over previous
//
#include <hip/hip_runtime.h>
#include <math.h>

#define NPTS 262144
#define BATCH 32
#define BPB 64
#define NBLK (BATCH * BPB)     // 2048 blocks x 256t (proven ~HBM-floor main)
#define NTAIL 40
#define THRESH (NBLK - NTAIL)  // 2008
#define S2N (16 + 24 * BATCH)  // 784

// ---------- wave (64-lane) reductions ----------
__device__ __forceinline__ float wred_sum(float v) {
#pragma unroll
    for (int o = 32; o; o >>= 1) v += __shfl_down(v, o);
    return v;
}
__device__ __forceinline__ unsigned wred_usum(unsigned v) {
#pragma unroll
    for (int o = 32; o; o >>= 1) v += __shfl_down(v, o);
    return v;
}

// relaxed agent-scope atomic load: reads at the device coherence point,
// NO buffer_inv (R9's failure was ACQUIRE/RELEASE cache maintenance).
__device__ __forceinline__ unsigned aload(const unsigned* p) {
    return __hip_atomic_load(p, __ATOMIC_RELAXED, __HIP_MEMORY_SCOPE_AGENT);
}

// Partials (no init needed -- every slot atomicExch'd before any read):
//   uint pf[27][NBLK] : float-bits; rows 0..4 S, 5..9 T, 10 lse,
//                       11..14 gtz, 15..18 prz, 19..26 minmax pairs
//   uint pi[9][NBLK]  : 0..4 bincount (1..4 double as gt counts), 5..8 prc
//   uint s2[S2N]      : float-bits stage-2 results
//   counters[2]       : arrival / tail-done  (8-byte memset per launch)

__global__ __launch_bounds__(256) void bsl_fused(
    const float* __restrict__ outputs, const int* __restrict__ labels,
    const float* __restrict__ points, unsigned* pf, unsigned* pi,
    unsigned* s2, unsigned* counters, float* out, int iters)
{
    const int blk = blockIdx.x;
    const int b = blk / BPB;
    const int seg = blk % BPB;
    const int seg_start = seg * (iters * 1024);
    const int tid = threadIdx.x;
    const int wid = tid >> 6, lane = tid & 63;

    // ================= main streaming pass (R8-identical, 60 VGPR) =========
    float S[5] = {0, 0, 0, 0, 0};
    float T[5] = {0, 0, 0, 0, 0};
    float lseacc = 0.f;
    float gtz[4] = {0, 0, 0, 0};
    float prz[4] = {0, 0, 0, 0};
    const float INF = __int_as_float(0x7f800000);
    float mn2x = INF, mx2x = -INF, mn2y = INF, mx2y = -INF;
    float mn3x = INF, mx3x = -INF, mn3y = INF, mx3y = -INF;
    unsigned bc[5] = {0, 0, 0, 0, 0}, prc[4] = {0, 0, 0, 0};

    const float* obase = outputs + (size_t)b * 5 * NPTS;
    const int*   lbase = labels + (size_t)b * NPTS;
    const float* pbase = points + (size_t)b * NPTS * 3;

    for (int it = 0; it < iters; ++it) {
        const int n = seg_start + it * 1024 + tid * 4;
        float4 L[5];
#pragma unroll
        for (int c = 0; c < 5; ++c)
            L[c] = *(const float4*)(obase + (size_t)c * NPTS + n);
        const int4 lab = *(const int4*)(lbase + n);
        const float4* pp = (const float4*)(pbase + (size_t)n * 3);
        const float4 p0 = pp[0], p1 = pp[1], p2 = pp[2];
        const float xs[4] = {p0.x, p0.w, p1.z, p2.y};
        const float ys[4] = {p0.y, p1.x, p1.w, p2.z};
        const float zs[4] = {p0.z, p1.y, p2.x, p2.w};
        const int   lb[4] = {lab.x, lab.y, lab.z, lab.w};
#pragma unroll
        for (int j = 0; j < 4; ++j) {
            float v[5];
#pragma unroll
            for (int c = 0; c < 5; ++c) v[c] = ((const float*)&L[c])[j];
            // first-max argmax (JAX tie-break semantics)
            float best = v[0]; int pred = 0;
#pragma unroll
            for (int c = 1; c < 5; ++c)
                if (v[c] > best) { best = v[c]; pred = c; }
            float e = 0.f;
#pragma unroll
            for (int c = 0; c < 5; ++c) e += __expf(v[c] - best);
            const float lse = best + __logf(e);
            lseacc += lse;
            const int y = lb[j];
#pragma unroll
            for (int c = 0; c < 5; ++c) {
                S[c] += v[c];
                const bool is = (y == c);
                T[c] += is ? (lse - v[c]) : 0.f;
                bc[c] += is ? 1u : 0u;
            }
            const float z = zs[j];
#pragma unroll
            for (int k = 0; k < 4; ++k) {
                const bool gy = (y == k + 1), py = (pred == k + 1);
                gtz[k] += gy ? z : 0.f;
                prz[k] += py ? z : 0.f;
                prc[k] += py ? 1u : 0u;
            }
            const float x = xs[j], yv = ys[j];
            // reference: mp = points*mask -> zeros included in min/max
            const float a2x = (pred == 2) ? x : 0.f;
            const float a2y = (pred == 2) ? yv : 0.f;
            const float a3x = (pred == 3) ? x : 0.f;
            const float a3y = (pred == 3) ? yv : 0.f;
            mn2x = fminf(mn2x, a2x); mx2x = fmaxf(mx2x, a2x);
            mn2y = fminf(mn2y, a2y); mx2y = fmaxf(mx2y, a2y);
            mn3x = fminf(mn3x, a3x); mx3x = fmaxf(mx3x, a3x);
            mn3y = fminf(mn3y, a3y); mx3y = fmaxf(mx3y, a3y);
        }
    }

    float fv[27] = {S[0], S[1], S[2], S[3], S[4],
                    T[0], T[1], T[2], T[3], T[4],
                    lseacc,
                    gtz[0], gtz[1], gtz[2], gtz[3],
                    prz[0], prz[1], prz[2], prz[3],
                    mn2x, mx2x, mn2y, mx2y, mn3x, mx3x, mn3y, mx3y};
    unsigned iv[9] = {bc[0], bc[1], bc[2], bc[3], bc[4],
                      prc[0], prc[1], prc[2], prc[3]};

    __shared__ float sf[4][27];
    __shared__ unsigned si[4][9];
#pragma unroll
    for (int vdx = 0; vdx < 27; ++vdx) {
        float r;
        if (vdx < 19) r = wred_sum(fv[vdx]);
        else if (((vdx - 19) & 1) == 0) {
#pragma unroll
            for (int o = 32; o; o >>= 1) fv[vdx] = fminf(fv[vdx], __shfl_down(fv[vdx], o));
            r = fv[vdx];
        } else {
#pragma unroll
            for (int o = 32; o; o >>= 1) fv[vdx] = fmaxf(fv[vdx], __shfl_down(fv[vdx], o));
            r = fv[vdx];
        }
        if (lane == 0) sf[wid][vdx] = r;
    }
#pragma unroll
    for (int vdx = 0; vdx < 9; ++vdx) {
        unsigned r = wred_usum(iv[vdx]);
        if (lane == 0) si[wid][vdx] = r;
    }
    __syncthreads();

    // cross-wave combine -> publish via relaxed atomicExch (RMW executes at
    // the coherence point: cross-XCD visible, NO wbl2/inv)
    unsigned dummy = 0u;
    if (tid < 27) {
        float r = sf[0][tid];
        if (tid < 19) {
            r += sf[1][tid] + sf[2][tid] + sf[3][tid];
        } else if (((tid - 19) & 1) == 0) {
            r = fminf(fminf(r, sf[1][tid]), fminf(sf[2][tid], sf[3][tid]));
        } else {
            r = fmaxf(fmaxf(r, sf[1][tid]), fmaxf(sf[2][tid], sf[3][tid]));
        }
        dummy = atomicExch(&pf[(size_t)tid * NBLK + blk], __float_as_uint(r));
    } else if (tid >= 32 && tid < 41) {
        const int v = tid - 32;
        dummy = atomicExch(&pi[(size_t)v * NBLK + blk],
                           si[0][v] + si[1][v] + si[2][v] + si[3][v]);
    }
    // hardware-completion ordering: the exchanges (all in wave 0) must have
    // executed at the coherence point before this block's arrival increment.
    asm volatile("" :: "v"(dummy));                       // keep result live
    asm volatile("s_waitcnt vmcnt(0)" ::: "memory");      // per-wave drain

    __shared__ int s_task;
    if (tid == 0)
        s_task = (int)atomicAdd(&counters[0], 1u) - THRESH;
    __syncthreads();
    const int t = s_task;
    if (t < 0) return;                                    // 2008 blocks exit

    // ============ tail: last 40 arrivals, one task each ====================
    if (tid == 0) {
        while (aload(&counters[0]) < (unsigned)NBLK)      // relaxed spin
            __builtin_amdgcn_s_sleep(8);
    }
    __syncthreads();

    __shared__ float red[4];
    unsigned dummy2 = 0u;
    if (t < 16) {
        // global row sum: 2048 values, 8 scalar atomic loads/thread
        float s = 0.f;
        if (t < 11) {
            const unsigned* row = pf + (size_t)t * NBLK;
#pragma unroll
            for (int k = 0; k < 8; ++k)
                s += __uint_as_float(aload(row + tid + k * 256));
        } else {
            const unsigned* row = pi + (size_t)(t - 11) * NBLK;
#pragma unroll
            for (int k = 0; k < 8; ++k)
                s += (float)aload(row + tid + k * 256);   // exact: ints < 2^24
        }
        s = wred_sum(s);
        if (lane == 0) red[wid] = s;
        __syncthreads();
        if (tid == 0)
            dummy2 = atomicExch(&s2[t],
                __float_as_uint(red[0] + red[1] + red[2] + red[3]));
    } else {
        // per-batch row: 32 batches x 64 values, 8 threads/batch
        const int f = t - 16;              // 0..23
        const int bb = tid >> 3, k = tid & 7;
        const int base = bb * BPB;
        float r;
        if (f < 8) {                       // gtz[4], prz[4] (pf rows 11..18)
            const unsigned* row = pf + (size_t)(11 + f) * NBLK + base;
            r = 0.f;
#pragma unroll
            for (int j = 0; j < 8; ++j) r += __uint_as_float(aload(row + k * 8 + j));
#pragma unroll
            for (int o = 4; o; o >>= 1) r += __shfl_xor(r, o);
        } else if (f < 16) {               // minmax (pf rows 19..26)
            const int g = f - 8;
            const unsigned* row = pf + (size_t)(19 + g) * NBLK + base;
            r = __uint_as_float(aload(row + k * 8));
            if ((g & 1) == 0) {
#pragma unroll
                for (int j = 1; j < 8; ++j) r = fminf(r, __uint_as_float(aload(row + k * 8 + j)));
#pragma unroll
                for (int o = 4; o; o >>= 1) r = fminf(r, __shfl_xor(r, o));
            } else {
#pragma unroll
                for (int j = 1; j < 8; ++j) r = fmaxf(r, __uint_as_float(aload(row + k * 8 + j)));
#pragma unroll
                for (int o = 4; o; o >>= 1) r = fmaxf(r, __shfl_xor(r, o));
            }
        } else {                           // gtc (pi rows 1..4), prc (rows 5..8)
            const int g = f - 16;
            const int rowi = (g < 4) ? (1 + g) : (5 + (g - 4));
            const unsigned* row = pi + (size_t)rowi * NBLK + base;
            r = 0.f;
#pragma unroll
            for (int j = 0; j < 8; ++j) r += (float)aload(row + k * 8 + j);
#pragma unroll
            for (int o = 4; o; o >>= 1) r += __shfl_xor(r, o);
        }
        if (k == 0)
            dummy2 = atomicExch(&s2[16 + bb * 24 + f], __float_as_uint(r));
    }
    asm volatile("" :: "v"(dummy2));
    asm volatile("s_waitcnt vmcnt(0)" ::: "memory");
    __syncthreads();

    __shared__ int s_fin;
    if (tid == 0)
        s_fin = (atomicAdd(&counters[1], 1u) == (unsigned)(NTAIL - 1)) ? 1 : 0;
    __syncthreads();
    if (!s_fin) return;                   // 39 tail blocks exit

    // ============ finalize (40th tail block) ===============================
    __shared__ float sm[S2N];
    for (int i = tid; i < S2N; i += 256)
        sm[i] = __uint_as_float(aload(&s2[i]));
    __syncthreads();
    if (wid != 0) return;

    const float BASE_W[5] = {0.8f, 2.0f, 1.5f, 1.5f, 3.5f};
    const int pc[12]  = {1, 1, 1, 2, 2, 2, 3, 3, 3, 4, 4, 4};
    const int prf[12] = {2, 3, 4, 1, 3, 4, 1, 2, 4, 1, 2, 3};
    const float ps[12] = {-1.f, -1.f, -1.f, 1.f, -1.f, -1.f, 1.f, 1.f, -1.f, 1.f, 1.f, 1.f};

    float w[5] = {0, 0, 0, 0, 0};
    if (lane < BATCH) {
        const float* R = sm + 16 + lane * 24;
        for (int c = 0; c < 5; ++c) w[c] = BASE_W[c];
        float gtm[4], prm[4];
        bool gv[4], pv[4];
#pragma unroll
        for (int k = 0; k < 4; ++k) {
            const float c1 = R[16 + k];
            gv[k] = (c1 > 0.f);
            gtm[k] = R[k] / fmaxf(c1, 1.f);
            const float c2 = R[20 + k];
            pv[k] = (c2 > 0.f);
            prm[k] = R[4 + k] / fmaxf(c2, 1.f);
        }
#pragma unroll
        for (int p = 0; p < 12; ++p) {
            const int cid = pc[p], ref = prf[p];
            float add = 0.f;
            if (pv[cid - 1] && gv[ref - 1]) {
                const float diff = ps[p] * (prm[cid - 1] - gtm[ref - 1]);
                add = 50.f / (1.f + expf(10.f * diff));  // ALPHA*sigmoid(-10*diff)
            }
            w[cid] += add;
            w[ref] += 0.3f * add;
        }
        const float mn2x_ = R[8],  mx2x_ = R[9],  mn2y_ = R[10], mx2y_ = R[11];
        const float mn3x_ = R[12], mx3x_ = R[13], mn3y_ = R[14], mx3y_ = R[15];
        {   // cid=2 vs rb=bounds[3]
            const float dx = mx3x_ - mn3x_ + 1e-7f, dy = mx3y_ - mn3y_ + 1e-7f;
            const float xc0 = (mn2x_ - mn3x_) / dx, xc1 = (mx2x_ - mn3x_) / dx;
            const float yc0 = (mn2y_ - mn3y_) / dy, yc1 = (mx2y_ - mn3y_) / dy;
            const float v0 = (xc0 < 0.1f || xc0 > 0.9f || yc0 < 0.1f || yc0 > 0.9f) ? 1.f : 0.f;
            const float v1 = (xc1 < 0.1f || xc1 > 0.9f || yc1 < 0.1f || yc1 > 0.9f) ? 1.f : 0.f;
            w[2] += 50.f * 0.5f * (v0 + v1);
        }
        {   // cid=3 vs rb=bounds[2]
            const float dx = mx2x_ - mn2x_ + 1e-7f, dy = mx2y_ - mn2y_ + 1e-7f;
            const float xc0 = (mn3x_ - mn2x_) / dx, xc1 = (mx3x_ - mn2x_) / dx;
            const float yc0 = (mn3y_ - mn2y_) / dy, yc1 = (mx3y_ - mn2y_) / dy;
            const float v0 = (xc0 < 0.1f || xc0 > 0.9f || yc0 < 0.1f || yc0 > 0.9f) ? 1.f : 0.f;
            const float v1 = (xc1 < 0.1f || xc1 > 0.9f || yc1 < 0.1f || yc1 > 0.9f) ? 1.f : 0.f;
            w[3] += 50.f * 0.5f * (v0 + v1);
        }
#pragma unroll
        for (int c = 0; c < 5; ++c)
            w[c] = fminf(fmaxf(w[c], 0.1f), 10.f);
    }
    float wsumc[5];
#pragma unroll
    for (int c = 0; c < 5; ++c) wsumc[c] = wred_sum(w[c]);

    if (lane == 0) {
        float dist[5], cw[5], s = 0.f;
#pragma unroll
        for (int c = 0; c < 5; ++c) {
            dist[c] = sm[11 + c];
            cw[c] = 1.f / (sqrtf(dist[c]) + 1e-7f);
            s += cw[c];
        }
        float wf[5], wsum = 0.f, W = 0.f, nllnum = 0.f, Ssum = 0.f;
#pragma unroll
        for (int c = 0; c < 5; ++c) {
            cw[c] = cw[c] / s * 5.f;
            wf[c] = (wsumc[c] / 32.f) * cw[c];
            wsum += wf[c] * dist[c];
            W += wf[c];
            nllnum += wf[c] * sm[5 + c];
            Ssum += wf[c] * sm[c];
        }
        const float nll = nllnum / wsum;
        const float smooth = (W * sm[10] - Ssum) / wsum;
        out[0] = 0.8f * nll + 0.04f * smooth;
    }
}

extern "C" void kernel_launch(void* const* d_in, const int* in_sizes, int n_in,
                              void* d_out, int out_size, void* d_ws, size_t ws_size,
                              hipStream_t stream) {
    const float* outputs = (const float*)d_in[0];
    const int*   labels  = (const int*)d_in[1];
    const float* points  = (const float*)d_in[2];
    float* out = (float*)d_out;

    char* base = (char*)d_ws;
    unsigned* counters = (unsigned*)base;                        // 2 u32
    unsigned* pf = (unsigned*)(base + 64);                       // 27*2048
    unsigned* pi = pf + (size_t)27 * NBLK;                       // 9*2048
    unsigned* s2 = pi + (size_t)9 * NBLK;                        // 784

    const int iters = NPTS / (BPB * 1024);                       // 4

    hipMemsetAsync(counters, 0, 8, stream);                      // only init
    bsl_fused<<<NBLK, 256, 0, stream>>>(outputs, labels, points,
                                        pf, pi, s2, counters, out, iters);
}

// Round 13
// 64.407 us; speedup vs baseline: 2.9856x; 1.1855x over previous
//
#include <hip/hip_runtime.h>
#include <math.h>

#define NPTS 262144
#define BATCH 32

// ---------- wave (64-lane) reductions ----------
__device__ __forceinline__ float wred_sum(float v) {
#pragma unroll
    for (int o = 32; o; o >>= 1) v += __shfl_down(v, o);
    return v;
}
__device__ __forceinline__ unsigned wred_usum(unsigned v) {
#pragma unroll
    for (int o = 32; o; o >>= 1) v += __shfl_down(v, o);
    return v;
}
__device__ __forceinline__ float wred_min(float v) {
#pragma unroll
    for (int o = 32; o; o >>= 1) v = fminf(v, __shfl_down(v, o));
    return v;
}
__device__ __forceinline__ float wred_max(float v) {
#pragma unroll
    for (int o = 32; o; o >>= 1) v = fmaxf(v, __shfl_down(v, o));
    return v;
}

// Partial layout in d_ws (nblk = BATCH*bpb = 512 -> 72 KB total):
//   float pf[27][nblk] : 0..4 S[c], 5..9 T[c], 10 lse_sum,
//                        11..14 gt z-sum (cls1..4), 15..18 pred z-sum,
//                        19..26 {mn2x,mx2x,mn2y,mx2y,mn3x,mx3x,mn3y,mx3y}
//   uint  pi[9][nblk]  : 0..4 bincount (rows 1..4 double as GT counts), 5..8 pred cnt

__global__ __launch_bounds__(256) void bsl_main(
    const float* __restrict__ outputs, const int* __restrict__ labels,
    const float* __restrict__ points, float* __restrict__ pf,
    unsigned int* __restrict__ pi, int bpb, int iters)
{
    const int blk = blockIdx.x;
    const int nblk = gridDim.x;
    const int b = blk / bpb;
    const int seg = blk % bpb;
    const int seg_start = seg * (iters * 1024);
    const int tid = threadIdx.x;

    float S[5] = {0, 0, 0, 0, 0};
    float T[5] = {0, 0, 0, 0, 0};
    float lseacc = 0.f;
    float gtz[4] = {0, 0, 0, 0};
    float prz[4] = {0, 0, 0, 0};
    const float INF = __int_as_float(0x7f800000);
    float mn2x = INF, mx2x = -INF, mn2y = INF, mx2y = -INF;
    float mn3x = INF, mx3x = -INF, mn3y = INF, mx3y = -INF;
    unsigned bc[5] = {0, 0, 0, 0, 0}, prc[4] = {0, 0, 0, 0};

    const float* obase = outputs + (size_t)b * 5 * NPTS;
    const int*   lbase = labels + (size_t)b * NPTS;
    const float* pbase = points + (size_t)b * NPTS * 3;

    for (int it = 0; it < iters; ++it) {
        const int n = seg_start + it * 1024 + tid * 4;
        float4 L[5];
#pragma unroll
        for (int c = 0; c < 5; ++c)
            L[c] = *(const float4*)(obase + (size_t)c * NPTS + n);
        const int4 lab = *(const int4*)(lbase + n);
        const float4* pp = (const float4*)(pbase + (size_t)n * 3);
        const float4 p0 = pp[0], p1 = pp[1], p2 = pp[2];
        const float xs[4] = {p0.x, p0.w, p1.z, p2.y};
        const float ys[4] = {p0.y, p1.x, p1.w, p2.z};
        const float zs[4] = {p0.z, p1.y, p2.x, p2.w};
        const int   lb[4] = {lab.x, lab.y, lab.z, lab.w};
#pragma unroll
        for (int j = 0; j < 4; ++j) {
            float v[5];
#pragma unroll
            for (int c = 0; c < 5; ++c) v[c] = ((const float*)&L[c])[j];
            // first-max argmax (JAX tie-break semantics)
            float best = v[0]; int pred = 0;
#pragma unroll
            for (int c = 1; c < 5; ++c)
                if (v[c] > best) { best = v[c]; pred = c; }
            float e = 0.f;
#pragma unroll
            for (int c = 0; c < 5; ++c) e += __expf(v[c] - best);
            const float lse = best + __logf(e);
            lseacc += lse;
            const int y = lb[j];
#pragma unroll
            for (int c = 0; c < 5; ++c) {
                S[c] += v[c];
                const bool is = (y == c);
                T[c] += is ? (lse - v[c]) : 0.f;
                bc[c] += is ? 1u : 0u;
            }
            const float z = zs[j];
#pragma unroll
            for (int k = 0; k < 4; ++k) {
                const bool gy = (y == k + 1), py = (pred == k + 1);
                gtz[k] += gy ? z : 0.f;
                prz[k] += py ? z : 0.f;
                prc[k] += py ? 1u : 0u;
            }
            const float x = xs[j], yv = ys[j];
            // reference: mp = points*mask -> zeros included in min/max
            const float a2x = (pred == 2) ? x : 0.f;
            const float a2y = (pred == 2) ? yv : 0.f;
            const float a3x = (pred == 3) ? x : 0.f;
            const float a3y = (pred == 3) ? yv : 0.f;
            mn2x = fminf(mn2x, a2x); mx2x = fmaxf(mx2x, a2x);
            mn2y = fminf(mn2y, a2y); mx2y = fmaxf(mx2y, a2y);
            mn3x = fminf(mn3x, a3x); mx3x = fmaxf(mx3x, a3x);
            mn3y = fminf(mn3y, a3y); mx3y = fmaxf(mx3y, a3y);
        }
    }

    float fv[27] = {S[0], S[1], S[2], S[3], S[4],
                    T[0], T[1], T[2], T[3], T[4],
                    lseacc,
                    gtz[0], gtz[1], gtz[2], gtz[3],
                    prz[0], prz[1], prz[2], prz[3],
                    mn2x, mx2x, mn2y, mx2y, mn3x, mx3x, mn3y, mx3y};
    unsigned iv[9] = {bc[0], bc[1], bc[2], bc[3], bc[4],
                      prc[0], prc[1], prc[2], prc[3]};

    __shared__ float sf[4][27];
    __shared__ unsigned si[4][9];
    const int wid = tid >> 6, lane = tid & 63;
#pragma unroll
    for (int vdx = 0; vdx < 27; ++vdx) {
        float r;
        if (vdx < 19) r = wred_sum(fv[vdx]);
        else if (((vdx - 19) & 1) == 0) r = wred_min(fv[vdx]);
        else r = wred_max(fv[vdx]);
        if (lane == 0) sf[wid][vdx] = r;
    }
#pragma unroll
    for (int vdx = 0; vdx < 9; ++vdx) {
        unsigned r = wred_usum(iv[vdx]);
        if (lane == 0) si[wid][vdx] = r;
    }
    __syncthreads();
    if (tid == 0) {
#pragma unroll
        for (int vdx = 0; vdx < 27; ++vdx) {
            float r;
            if (vdx < 19) r = sf[0][vdx] + sf[1][vdx] + sf[2][vdx] + sf[3][vdx];
            else if (((vdx - 19) & 1) == 0)
                r = fminf(fminf(sf[0][vdx], sf[1][vdx]), fminf(sf[2][vdx], sf[3][vdx]));
            else
                r = fmaxf(fmaxf(sf[0][vdx], sf[1][vdx]), fmaxf(sf[2][vdx], sf[3][vdx]));
            pf[(size_t)vdx * nblk + blk] = r;
        }
#pragma unroll
        for (int vdx = 0; vdx < 9; ++vdx)
            pi[(size_t)vdx * nblk + blk] = si[0][vdx] + si[1][vdx] + si[2][vdx] + si[3][vdx];
    }
}

// Single-block reduce + finalize over a SMALL (72 KB) partial matrix.
// One CU sustains only ~11-25 GB/s from HBM, so keeping the partials tiny is
// what makes a single-block tail viable (~3 us streaming + 1 latency round).
// Stage A: wave w sums global row w (11 float rows + 5 bincount rows).
// Stage B: thread t (<24*BATCH) handles one per-batch subtask (bpb els).
// Kernel boundary provides the device-wide fence (no threadfence/atomics --
// measured: each device-scope fence costs ~0.4-0.5 us of wbl2, R4/R8/R9/R12).
__global__ __launch_bounds__(1024) void bsl_reduce_final(
    const float* __restrict__ pf, const unsigned int* __restrict__ pi,
    int bpb, float* __restrict__ out)
{
    const int nblk = BATCH * bpb;
    const int tid = threadIdx.x;
    const int wid = tid >> 6, lane = tid & 63;
    const float INF = __int_as_float(0x7f800000);
    __shared__ float sm[16 + 24 * BATCH];

    // ---- stage A: global rows, one wave per row ----
    {
        float s = 0.f;
        const int n4 = nblk >> 2;
        if (wid < 11) {
            const float4* p4 = (const float4*)(pf + (size_t)wid * nblk);
#pragma unroll 2
            for (int i = lane; i < n4; i += 64) {
                const float4 v = p4[i];
                s += (v.x + v.y) + (v.z + v.w);
            }
        } else {
            const uint4* p4 = (const uint4*)(pi + (size_t)(wid - 11) * nblk);
#pragma unroll 2
            for (int i = lane; i < n4; i += 64) {
                const uint4 u = p4[i];
                s += ((float)u.x + (float)u.y) + ((float)u.z + (float)u.w);
            }
        }
        s = wred_sum(s);
        if (lane == 0) sm[wid] = s;   // wid 0..10: S,T,lse ; 11..15: dist
    }

    // ---- stage B: per-batch subtasks, one thread each ----
    if (tid < 24 * BATCH) {
        const int b = tid / 24;
        const int f = tid % 24;
        const int base = b * bpb;
        const int q4 = bpb >> 2;
        float r;
        if (f < 8) {                      // gtz[4], prz[4]: sums of rows 11..18
            const float4* p4 = (const float4*)(pf + (size_t)(11 + f) * nblk + base);
            float s = 0.f;
#pragma unroll 4
            for (int i = 0; i < q4; ++i) {
                const float4 v = p4[i];
                s += (v.x + v.y) + (v.z + v.w);
            }
            r = s;
        } else if (f < 16) {              // minmax: rows 19..26
            const int g = f - 8;
            const bool ismin = ((g & 1) == 0);
            const float4* p4 = (const float4*)(pf + (size_t)(19 + g) * nblk + base);
            float s = ismin ? INF : -INF;
#pragma unroll 4
            for (int i = 0; i < q4; ++i) {
                const float4 v = p4[i];
                if (ismin) s = fminf(s, fminf(fminf(v.x, v.y), fminf(v.z, v.w)));
                else       s = fmaxf(s, fmaxf(fmaxf(v.x, v.y), fmaxf(v.z, v.w)));
            }
            r = s;
        } else {                          // gtc (== bincount rows 1..4), prc (rows 5..8)
            const int g = f - 16;
            const int row = (g < 4) ? (1 + g) : (5 + (g - 4));
            const uint4* p4 = (const uint4*)(pi + (size_t)row * nblk + base);
            float s = 0.f;
#pragma unroll 4
            for (int i = 0; i < q4; ++i) {
                const uint4 u = p4[i];
                s += ((float)u.x + (float)u.y) + ((float)u.z + (float)u.w);
            }
            r = s;
        }
        sm[16 + tid] = r;
    }
    __syncthreads();
    if (wid != 0) return;                 // finalize on wave 0

    const float BASE_W[5] = {0.8f, 2.0f, 1.5f, 1.5f, 3.5f};
    const int pc[12]  = {1, 1, 1, 2, 2, 2, 3, 3, 3, 4, 4, 4};
    const int prf[12] = {2, 3, 4, 1, 3, 4, 1, 2, 4, 1, 2, 3};
    const float ps[12] = {-1.f, -1.f, -1.f, 1.f, -1.f, -1.f, 1.f, 1.f, -1.f, 1.f, 1.f, 1.f};

    // lane b (< BATCH) computes batch b's clipped weights; others contribute 0
    float w[5] = {0, 0, 0, 0, 0};
    if (lane < BATCH) {
        const float* R = sm + 16 + lane * 24;
        for (int c = 0; c < 5; ++c) w[c] = BASE_W[c];
        float gtm[4], prm[4];
        bool gv[4], pv[4];
#pragma unroll
        for (int k = 0; k < 4; ++k) {
            const float c1 = R[16 + k];
            gv[k] = (c1 > 0.f);
            gtm[k] = R[k] / fmaxf(c1, 1.f);
            const float c2 = R[20 + k];
            pv[k] = (c2 > 0.f);
            prm[k] = R[4 + k] / fmaxf(c2, 1.f);
        }
#pragma unroll
        for (int p = 0; p < 12; ++p) {
            const int cid = pc[p], ref = prf[p];
            float add = 0.f;
            if (pv[cid - 1] && gv[ref - 1]) {
                const float diff = ps[p] * (prm[cid - 1] - gtm[ref - 1]);
                add = 50.f / (1.f + expf(10.f * diff));  // ALPHA*sigmoid(-10*diff)
            }
            w[cid] += add;
            w[ref] += 0.3f * add;
        }
        const float mn2x = R[8],  mx2x = R[9],  mn2y = R[10], mx2y = R[11];
        const float mn3x = R[12], mx3x = R[13], mn3y = R[14], mx3y = R[15];
        {   // cid=2 vs rb=bounds[3]
            const float dx = mx3x - mn3x + 1e-7f, dy = mx3y - mn3y + 1e-7f;
            const float xc0 = (mn2x - mn3x) / dx, xc1 = (mx2x - mn3x) / dx;
            const float yc0 = (mn2y - mn3y) / dy, yc1 = (mx2y - mn3y) / dy;
            const float v0 = (xc0 < 0.1f || xc0 > 0.9f || yc0 < 0.1f || yc0 > 0.9f) ? 1.f : 0.f;
            const float v1 = (xc1 < 0.1f || xc1 > 0.9f || yc1 < 0.1f || yc1 > 0.9f) ? 1.f : 0.f;
            w[2] += 50.f * 0.5f * (v0 + v1);
        }
        {   // cid=3 vs rb=bounds[2]
            const float dx = mx2x - mn2x + 1e-7f, dy = mx2y - mn2y + 1e-7f;
            const float xc0 = (mn3x - mn2x) / dx, xc1 = (mx3x - mn2x) / dx;
            const float yc0 = (mn3y - mn2y) / dy, yc1 = (mx3y - mn2y) / dy;
            const float v0 = (xc0 < 0.1f || xc0 > 0.9f || yc0 < 0.1f || yc0 > 0.9f) ? 1.f : 0.f;
            const float v1 = (xc1 < 0.1f || xc1 > 0.9f || yc1 < 0.1f || yc1 > 0.9f) ? 1.f : 0.f;
            w[3] += 50.f * 0.5f * (v0 + v1);
        }
#pragma unroll
        for (int c = 0; c < 5; ++c)
            w[c] = fminf(fmaxf(w[c], 0.1f), 10.f);
    }
    float wsumc[5];
#pragma unroll
    for (int c = 0; c < 5; ++c) wsumc[c] = wred_sum(w[c]);

    if (lane == 0) {
        float dist[5], cw[5], s = 0.f;
#pragma unroll
        for (int c = 0; c < 5; ++c) {
            dist[c] = sm[11 + c];
            cw[c] = 1.f / (sqrtf(dist[c]) + 1e-7f);
            s += cw[c];
        }
        float wf[5], wsum = 0.f, W = 0.f, nllnum = 0.f, Ssum = 0.f;
#pragma unroll
        for (int c = 0; c < 5; ++c) {
            cw[c] = cw[c] / s * 5.f;
            wf[c] = (wsumc[c] / 32.f) * cw[c];
            wsum += wf[c] * dist[c];
            W += wf[c];
            nllnum += wf[c] * sm[5 + c];
            Ssum += wf[c] * sm[c];
        }
        const float nll = nllnum / wsum;
        const float smooth = (W * sm[10] - Ssum) / wsum;
        out[0] = 0.8f * nll + 0.04f * smooth;
    }
}

extern "C" void kernel_launch(void* const* d_in, const int* in_sizes, int n_in,
                              void* d_out, int out_size, void* d_ws, size_t ws_size,
                              hipStream_t stream) {
    const float* outputs = (const float*)d_in[0];
    const int*   labels  = (const int*)d_in[1];
    const float* points  = (const float*)d_in[2];
    float* out = (float*)d_out;

    int bpb = 16;  // 512 blocks total: best measured config (R6, 64.2 us)
    while (bpb > 4 &&
           (size_t)(27 + 9) * 4 * BATCH * (size_t)bpb > ws_size)
        bpb >>= 1;
    const int nblk = BATCH * bpb;
    const int iters = NPTS / (bpb * 1024);

    float* pf = (float*)d_ws;
    unsigned int* pi = (unsigned int*)(pf + (size_t)27 * nblk);

    bsl_main<<<nblk, 256, 0, stream>>>(outputs, labels, points, pf, pi, bpb, iters);
    bsl_reduce_final<<<1, 1024, 0, stream>>>(pf, pi, bpb, out);
}